// Round 10
// baseline (242.214 us; speedup 1.0000x reference)
//
#include <hip/hip_runtime.h>
#include <hip/hip_bf16.h>
#include <math.h>

#define NB 4096     // batch (= B); label of row n is labels[n % NB]
#define NN 8192     // N = B * n_views
#define DD 128      // feature dim
#define NCLS 100    // label values 0..99
#define NSPLIT 32   // j-splits; 256 cols per block
#define CHUNK 64    // cols per LDS-staged chunk
#define NCHUNK 4    // 256 / 64
#define NRB 32      // row-blocks of 256 rows

constexpr float INV_T = 14.285714285714286f;   // 1/0.07 (= subtracted row max M)
constexpr float EC1   = 20.609929155556620f;   // INV_T * log2(e)
constexpr float EC0   = -20.609929155556620f;  // -INV_T * log2(e)
constexpr float LN2   = 0.6931471805599453f;

typedef __attribute__((ext_vector_type(8))) short bf16x8;
typedef __attribute__((ext_vector_type(4))) float f32x4;

__device__ __forceinline__ float bf2f(ushort u) {
    union { unsigned int i; float f; } v; v.i = ((unsigned int)u) << 16; return v.f;
}

// ---- kernel 1: normalize -> bf16 + selfdot; zero S/counts/out; count labels ----
__global__ __launch_bounds__(256) void k_norm(const float* __restrict__ feat,
                                              ushort* __restrict__ fb,
                                              float* __restrict__ selfdot,
                                              float* __restrict__ zS,   // S (12800 f32) + counts (100 i32)
                                              int* __restrict__ counts,
                                              float* __restrict__ out) {
    const int gid = blockIdx.x * 256 + threadIdx.x;
    if (gid < NCLS * DD + NCLS) zS[gid] = 0.0f;   // bit-zero == int 0
    if (gid == 0) out[0] = 0.0f;

    const int r    = gid >> 6;                    // one wave per row
    const int lane = threadIdx.x & 63;
    const float2 v = ((const float2*)(feat + (size_t)r * DD))[lane];
    float ss = v.x * v.x + v.y * v.y;
#pragma unroll
    for (int off = 1; off < 64; off <<= 1) ss += __shfl_xor(ss, off, 64);
    const float scale = 1.0f / fmaxf(sqrtf(ss), 1e-12f);
    __hip_bfloat162 h2;
    h2.x = __float2bfloat16(v.x * scale);
    h2.y = __float2bfloat16(v.y * scale);
    ((__hip_bfloat162*)(fb + (size_t)r * DD))[lane] = h2;
    // self-dot of the QUANTIZED row (matches the MFMA diagonal)
    const float xb = bf2f(((ushort2*)&h2)->x), yb = bf2f(((ushort2*)&h2)->y);
    float s2 = xb * xb + yb * yb;
#pragma unroll
    for (int off = 1; off < 64; off <<= 1) s2 += __shfl_xor(s2, off, 64);
    if (lane == 0) selfdot[r] = s2;
}

// ---- kernel 2: class sums S_c via LDS accumulation (16 blocks x 256 rows) ----
// Positive set of row i is {m : labels[m % NB] == labels[i % NB]}, so
// S_c = sum over batch b with labels[b]==c of (fb[b] + fb[b+NB]).
__global__ __launch_bounds__(256) void k_csum(const ushort* __restrict__ fb,
                                              const int* __restrict__ labels,
                                              float* __restrict__ S,
                                              int* __restrict__ counts) {
    __shared__ float Sl[NCLS * DD];               // 51.2 KB
    const int tid = threadIdx.x;
    for (int i = tid; i < NCLS * DD; i += 256) Sl[i] = 0.0f;
    __syncthreads();
    const int b0   = blockIdx.x * 256;
    const int d    = tid & 127;
    const int half = tid >> 7;                    // which view-row of the pair
    int cnt_local = 0;
    for (int i = 0; i < 256; ++i) {
        const int b = b0 + i;
        const int c = labels[b];                  // uniform scalar load
        atomicAdd(&Sl[c * DD + d], bf2f(fb[(size_t)(b + half * NB) * DD + d]));
        cnt_local += (tid == 0) ? 0 : 0;
    }
    __syncthreads();
    for (int i = tid; i < NCLS * DD; i += 256) atomicAdd(&S[i], Sl[i]);
    // per-class batch counts (one block only, 100 classes, serial-free)
    if (blockIdx.x == 0 && tid < 256) {
        // each thread scans a 16-entry strip; 4096/256 = 16
        for (int b = tid * 16; b < tid * 16 + 16; ++b)
            atomicAdd(&counts[labels[b]], 1);
    }
}

// stage one 64-col chunk's B-fragments into LDS, fragment-major, 4 waves.
// Pair p = jt*4+kt (16 pairs); wave w stages pairs 4w..4w+3.
// LDS dst = wave-uniform base + lane*16 (HW rule); per-lane GLOBAL address
// does the fragment gather.
__device__ __forceinline__ void stage_chunk(const ushort* __restrict__ fb, ushort* sbuf,
                                            int jb, int w, int n15, int q) {
#pragma unroll
    for (int h = 0; h < 4; ++h) {
        const int p = w * 4 + h;
        const ushort* g = fb + (size_t)(jb + (p >> 2) * 16 + n15) * DD + (p & 3) * 32 + q * 8;
        __builtin_amdgcn_global_load_lds(
            (const __attribute__((address_space(1))) void*)g,
            (__attribute__((address_space(3))) void*)(sbuf + p * 512),
            16, 0, 0);
    }
}

// ---- kernel 3: F*F^T row-sumexp ONLY. Wave = 64 rows x 256 cols. ----
// 16 MFMA per 4 ds_read_b128 -> MFMA-bound. No labels, no masks, 1 accumulator
// array. Grid 1024 = 32 rb x 32 js -> 4 blocks/CU, 16 waves/CU.
__global__ __launch_bounds__(256, 4) void k_main(const ushort* __restrict__ fb,
                                                 float* __restrict__ g_se) {
    __shared__ ushort sB[2][CHUNK * DD];          // 2 x 16 KB, fragment-major

    const int tid  = threadIdx.x;
    const int lane = tid & 63;
    const int w    = tid >> 6;                    // 0..3
    const int rb   = blockIdx.x >> 5;             // 0..31
    const int js   = blockIdx.x & (NSPLIT - 1);   // 0..31
    const int i0   = rb * 256 + w * 64;
    const int jb0  = js * 256;
    const int q    = lane >> 4;
    const int n15  = lane & 15;

    // A fragments: 4 row-tiles x 4 kt (64 regs), resident whole kernel
    bf16x8 afrag[4][4];
#pragma unroll
    for (int tt = 0; tt < 4; ++tt) {
        const ushort* rp = fb + (size_t)(i0 + tt * 16 + n15) * DD + q * 8;
#pragma unroll
        for (int kt = 0; kt < 4; ++kt) afrag[tt][kt] = *(const bf16x8*)(rp + kt * 32);
    }

    float a_se[16] = {};

    stage_chunk(fb, &sB[0][0], jb0, w, n15, q);
    __syncthreads();

    for (int c = 0; c < NCHUNK; ++c) {
        if (c + 1 < NCHUNK)
            stage_chunk(fb, &sB[(c + 1) & 1][0], jb0 + (c + 1) * CHUNK, w, n15, q);
        const ushort* sb = &sB[c & 1][0];
#pragma unroll
        for (int jt = 0; jt < 4; ++jt) {
            bf16x8 bf[4];
#pragma unroll
            for (int kt = 0; kt < 4; ++kt)
                bf[kt] = *(const bf16x8*)(sb + (jt * 4 + kt) * 512 + lane * 8); // conflict-free
            // two half-passes of 2 row-tiles each: keeps transient acc at 8 regs
#pragma unroll
            for (int h = 0; h < 2; ++h) {
                f32x4 a0 = {0.f, 0.f, 0.f, 0.f}, a1 = {0.f, 0.f, 0.f, 0.f};
#pragma unroll
                for (int kt = 0; kt < 4; ++kt) {
                    a0 = __builtin_amdgcn_mfma_f32_16x16x32_bf16(afrag[2 * h][kt],     bf[kt], a0, 0, 0, 0);
                    a1 = __builtin_amdgcn_mfma_f32_16x16x32_bf16(afrag[2 * h + 1][kt], bf[kt], a1, 0, 0, 0);
                }
#pragma unroll
                for (int r = 0; r < 4; ++r) {
                    a_se[(2 * h) * 4 + r]     += __builtin_amdgcn_exp2f(fmaf(a0[r], EC1, EC0));
                    a_se[(2 * h + 1) * 4 + r] += __builtin_amdgcn_exp2f(fmaf(a1[r], EC1, EC0));
                }
            }
        }
        __syncthreads();
    }

    // 16 lanes per quad share the same rows; reduce, single plain store each
#pragma unroll
    for (int s = 0; s < 16; ++s) {
        float v = a_se[s];
#pragma unroll
        for (int off = 1; off < 16; off <<= 1) v += __shfl_xor(v, off, 64);
        if (n15 == 0)
            g_se[js * NN + i0 + (s >> 2) * 16 + q * 4 + (s & 3)] = v;
    }
}

// ---- kernel 4: per-row loss via algebraic possum -> atomic mean ----
__global__ __launch_bounds__(256) void k_final(const ushort* __restrict__ fb,
                                               const int* __restrict__ labels,
                                               const float* __restrict__ g_se,
                                               const float* __restrict__ S,
                                               const int* __restrict__ counts,
                                               const float* __restrict__ selfdot,
                                               float* __restrict__ out) {
    const int r = blockIdx.x * 256 + threadIdx.x;
    const int c = labels[r & (NB - 1)];
    float se = 0.0f;
#pragma unroll
    for (int t = 0; t < NSPLIT; ++t) se += g_se[t * NN + r];

    // s1 = dot(f_i, S_c) in fp32 from the bf16 row
    const ushort* fp = fb + (size_t)r * DD;
    const float*  sp = S + c * DD;
    float s1 = 0.0f;
#pragma unroll
    for (int k = 0; k < DD; k += 4) {
        ushort4 u = *(const ushort4*)(fp + k);
        float4 sv = *(const float4*)(sp + k);
        s1 = fmaf(bf2f(u.x), sv.x, fmaf(bf2f(u.y), sv.y,
             fmaf(bf2f(u.z), sv.z, fmaf(bf2f(u.w), sv.w, s1))));
    }
    const float sd = selfdot[r];
    se -= __builtin_amdgcn_exp2f(fmaf(sd, EC1, EC0));  // drop diagonal from sumexp
    const float ct = (float)(2 * counts[c] - 1);
    const float possum = INV_T * (s1 - sd - ct);       // sum_pos (l_ij - M)
    const float lg  = __builtin_amdgcn_logf(se + 1e-12f) * LN2;
    const float mlpp = (possum - ct * lg) / fmaxf(ct, 1.0f);
    float v = -mlpp * (1.0f / (float)NN);
#pragma unroll
    for (int off = 1; off < 64; off <<= 1) v += __shfl_xor(v, off, 64);
    __shared__ float sred[4];
    if ((threadIdx.x & 63) == 0) sred[threadIdx.x >> 6] = v;
    __syncthreads();
    if (threadIdx.x == 0) atomicAdd(out, sred[0] + sred[1] + sred[2] + sred[3]);
}

extern "C" void kernel_launch(void* const* d_in, const int* in_sizes, int n_in,
                              void* d_out, int out_size, void* d_ws, size_t ws_size,
                              hipStream_t stream) {
    const float* feat = (const float*)d_in[0];
    const int* labels = (const int*)d_in[1];
    float* out        = (float*)d_out;
    char* ws          = (char*)d_ws;

    ushort* fb      = (ushort*)ws;                                   // 2 MB
    float* g_se     = (float*)(ws + (size_t)2 * 1024 * 1024);        // [32][NN] = 1 MB
    float* selfdot  = g_se + NSPLIT * NN;                            // NN f32
    float* S        = selfdot + NN;                                  // 12800 f32
    int*   counts   = (int*)(S + NCLS * DD);                         // 100 i32 (zeroed with S)

    k_norm<<<NN / 4, 256, 0, stream>>>(feat, fb, selfdot, S, counts, out);
    k_csum<<<NB / 256, 256, 0, stream>>>(fb, labels, S, counts);
    k_main<<<NRB * NSPLIT, 256, 0, stream>>>(fb, g_se);
    k_final<<<NN / 256, 256, 0, stream>>>(fb, labels, g_se, S, counts, selfdot, out);
}

// Round 11
// 102.770 us; speedup vs baseline: 2.3568x; 2.3568x over previous
//
#include <hip/hip_runtime.h>
#include <hip/hip_bf16.h>
#include <math.h>

#define NB 4096     // batch (= B); label of row n is labels[n % NB]
#define NN 8192     // N = B * n_views
#define DD 128      // feature dim
#define NCLS 100    // label values 0..99
#define NSPLIT 32   // j-splits; 256 cols per block
#define CHUNK 64    // cols per LDS-staged chunk
#define NCHUNK 4    // 256 / 64
#define NRB 32      // row-blocks of 256 rows

constexpr float INV_T = 14.285714285714286f;   // 1/0.07 (= subtracted row max M)
constexpr float EC1   = 20.609929155556620f;   // INV_T * log2(e)
constexpr float EC0   = -20.609929155556620f;  // -INV_T * log2(e)
constexpr float LN2   = 0.6931471805599453f;

typedef __attribute__((ext_vector_type(8))) short bf16x8;
typedef __attribute__((ext_vector_type(4))) float f32x4;

__device__ __forceinline__ float bf2f(ushort u) {
    union { unsigned int i; float f; } v; v.i = ((unsigned int)u) << 16; return v.f;
}

// ---- kernel 1: L2-normalize rows -> bf16 + selfdot; zero the output scalar ----
__global__ __launch_bounds__(256) void k_norm(const float* __restrict__ feat,
                                              ushort* __restrict__ fb,
                                              float* __restrict__ selfdot,
                                              float* __restrict__ out) {
    const int gid = blockIdx.x * 256 + threadIdx.x;
    if (gid == 0) out[0] = 0.0f;               // k_final atomicAdds into out
    const int r    = gid >> 6;                 // one wave per row
    const int lane = threadIdx.x & 63;
    const float2 v = ((const float2*)(feat + (size_t)r * DD))[lane];
    float ss = v.x * v.x + v.y * v.y;
#pragma unroll
    for (int off = 1; off < 64; off <<= 1) ss += __shfl_xor(ss, off, 64);
    const float scale = 1.0f / fmaxf(sqrtf(ss), 1e-12f);
    __hip_bfloat162 h2;
    h2.x = __float2bfloat16(v.x * scale);
    h2.y = __float2bfloat16(v.y * scale);
    ((__hip_bfloat162*)(fb + (size_t)r * DD))[lane] = h2;
    // self-dot of the QUANTIZED row (matches the MFMA diagonal)
    const float xb = bf2f(((ushort2*)&h2)->x), yb = bf2f(((ushort2*)&h2)->y);
    float s2 = xb * xb + yb * yb;
#pragma unroll
    for (int off = 1; off < 64; off <<= 1) s2 += __shfl_xor(s2, off, 64);
    if (lane == 0) selfdot[r] = s2;
}

// ---- kernel 2: class sums S_c, one block per class (100-way parallel) ----
// Block owns its class -> plain stores, no global atomics, no zero-init.
__global__ __launch_bounds__(256) void k_csum(const ushort* __restrict__ fb,
                                              const int* __restrict__ labels,
                                              float* __restrict__ S,
                                              int* __restrict__ counts) {
    __shared__ int list[NB];       // match list (worst case all of batch)
    __shared__ float Sl[256];
    __shared__ int lcnt;
    const int tid = threadIdx.x;
    const int c   = blockIdx.x;
    if (tid == 0) lcnt = 0;
    __syncthreads();
    for (int b = tid; b < NB; b += 256)
        if (labels[b] == c) list[atomicAdd(&lcnt, 1)] = b;
    __syncthreads();
    const int cnt = lcnt;
    const int d = tid & 127;
    const int h = tid >> 7;        // which view-row of the pair
    float acc0 = 0.0f, acc1 = 0.0f;
    int i = 0;
    for (; i + 1 < cnt; i += 2) {  // 2-way unroll: independent loads in flight
        const int b0 = list[i], b1 = list[i + 1];
        acc0 += bf2f(fb[(size_t)(b0 + h * NB) * DD + d]);
        acc1 += bf2f(fb[(size_t)(b1 + h * NB) * DD + d]);
    }
    if (i < cnt) acc0 += bf2f(fb[(size_t)(list[i] + h * NB) * DD + d]);
    Sl[tid] = acc0 + acc1;
    __syncthreads();
    if (tid < 128) S[c * DD + tid] = Sl[tid] + Sl[tid + 128];
    if (tid == 0) counts[c] = cnt;
}

// stage one 64-col chunk's B-fragments into LDS, fragment-major, 4 waves.
// Pair p = jt*4+kt (16 pairs); wave w stages pairs 4w..4w+3.
// LDS dst = wave-uniform base + lane*16 (HW rule); per-lane GLOBAL address
// does the fragment gather.
__device__ __forceinline__ void stage_chunk(const ushort* __restrict__ fb, ushort* sbuf,
                                            int jb, int w, int n15, int q) {
#pragma unroll
    for (int h = 0; h < 4; ++h) {
        const int p = w * 4 + h;
        const ushort* g = fb + (size_t)(jb + (p >> 2) * 16 + n15) * DD + (p & 3) * 32 + q * 8;
        __builtin_amdgcn_global_load_lds(
            (const __attribute__((address_space(1))) void*)g,
            (__attribute__((address_space(3))) void*)(sbuf + p * 512),
            16, 0, 0);
    }
}

// ---- kernel 3: F*F^T row-sumexp ONLY. Wave = 64 rows x 256 cols. ----
// 16 MFMA per 4 ds_read_b128 -> MFMA-bound. launch_bounds (256,2): 256-reg
// budget so afrag[4][4]+a_se[16] fit WITHOUT scratch spill (R10 lesson:
// (256,4) forced a 128-reg budget -> spill -> 325 MB scratch traffic).
// Grid 1024 = 32 rb x 32 js; LDS 32.8 KB still allows up to 4 blocks/CU.
__global__ __launch_bounds__(256, 2) void k_main(const ushort* __restrict__ fb,
                                                 float* __restrict__ g_se) {
    __shared__ ushort sB[2][CHUNK * DD];          // 2 x 16 KB, fragment-major

    const int tid  = threadIdx.x;
    const int lane = tid & 63;
    const int w    = tid >> 6;                    // 0..3
    const int rb   = blockIdx.x >> 5;             // 0..31
    const int js   = blockIdx.x & (NSPLIT - 1);   // 0..31
    const int i0   = rb * 256 + w * 64;
    const int jb0  = js * 256;
    const int q    = lane >> 4;
    const int n15  = lane & 15;

    // A fragments: 4 row-tiles x 4 kt (64 regs), resident whole kernel
    bf16x8 afrag[4][4];
#pragma unroll
    for (int tt = 0; tt < 4; ++tt) {
        const ushort* rp = fb + (size_t)(i0 + tt * 16 + n15) * DD + q * 8;
#pragma unroll
        for (int kt = 0; kt < 4; ++kt) afrag[tt][kt] = *(const bf16x8*)(rp + kt * 32);
    }

    float a_se[16] = {};

    stage_chunk(fb, &sB[0][0], jb0, w, n15, q);
    __syncthreads();

    for (int c = 0; c < NCHUNK; ++c) {
        if (c + 1 < NCHUNK)
            stage_chunk(fb, &sB[(c + 1) & 1][0], jb0 + (c + 1) * CHUNK, w, n15, q);
        const ushort* sb = &sB[c & 1][0];
#pragma unroll
        for (int jt = 0; jt < 4; ++jt) {
            bf16x8 bf[4];
#pragma unroll
            for (int kt = 0; kt < 4; ++kt)
                bf[kt] = *(const bf16x8*)(sb + (jt * 4 + kt) * 512 + lane * 8); // conflict-free
            // two half-passes of 2 row-tiles each: transient acc stays at 8 regs
#pragma unroll
            for (int h = 0; h < 2; ++h) {
                f32x4 a0 = {0.f, 0.f, 0.f, 0.f}, a1 = {0.f, 0.f, 0.f, 0.f};
#pragma unroll
                for (int kt = 0; kt < 4; ++kt) {
                    a0 = __builtin_amdgcn_mfma_f32_16x16x32_bf16(afrag[2 * h][kt],     bf[kt], a0, 0, 0, 0);
                    a1 = __builtin_amdgcn_mfma_f32_16x16x32_bf16(afrag[2 * h + 1][kt], bf[kt], a1, 0, 0, 0);
                }
#pragma unroll
                for (int r = 0; r < 4; ++r) {
                    a_se[(2 * h) * 4 + r]     += __builtin_amdgcn_exp2f(fmaf(a0[r], EC1, EC0));
                    a_se[(2 * h + 1) * 4 + r] += __builtin_amdgcn_exp2f(fmaf(a1[r], EC1, EC0));
                }
            }
        }
        __syncthreads();
    }

    // 16 lanes per quad share the same rows; reduce, single plain store each
#pragma unroll
    for (int s = 0; s < 16; ++s) {
        float v = a_se[s];
#pragma unroll
        for (int off = 1; off < 16; off <<= 1) v += __shfl_xor(v, off, 64);
        if (n15 == 0)
            g_se[js * NN + i0 + (s >> 2) * 16 + q * 4 + (s & 3)] = v;
    }
}

// ---- kernel 4: per-row loss via algebraic possum -> atomic mean ----
__global__ __launch_bounds__(256) void k_final(const ushort* __restrict__ fb,
                                               const int* __restrict__ labels,
                                               const float* __restrict__ g_se,
                                               const float* __restrict__ S,
                                               const int* __restrict__ counts,
                                               const float* __restrict__ selfdot,
                                               float* __restrict__ out) {
    const int r = blockIdx.x * 256 + threadIdx.x;
    const int c = labels[r & (NB - 1)];
    float se = 0.0f;
#pragma unroll
    for (int t = 0; t < NSPLIT; ++t) se += g_se[t * NN + r];

    // s1 = dot(f_i, S_c) in fp32 from the bf16 row
    const ushort* fp = fb + (size_t)r * DD;
    const float*  sp = S + c * DD;
    float s1 = 0.0f;
#pragma unroll
    for (int k = 0; k < DD; k += 4) {
        ushort4 u = *(const ushort4*)(fp + k);
        float4 sv = *(const float4*)(sp + k);
        s1 = fmaf(bf2f(u.x), sv.x, fmaf(bf2f(u.y), sv.y,
             fmaf(bf2f(u.z), sv.z, fmaf(bf2f(u.w), sv.w, s1))));
    }
    const float sd = selfdot[r];
    se -= __builtin_amdgcn_exp2f(fmaf(sd, EC1, EC0));  // drop diagonal from sumexp
    const float ct = (float)(2 * counts[c] - 1);
    const float possum = INV_T * (s1 - sd - ct);       // sum_pos (l_ij - M)
    const float lg  = __builtin_amdgcn_logf(se + 1e-12f) * LN2;
    const float mlpp = (possum - ct * lg) / fmaxf(ct, 1.0f);
    float v = -mlpp * (1.0f / (float)NN);
#pragma unroll
    for (int off = 1; off < 64; off <<= 1) v += __shfl_xor(v, off, 64);
    __shared__ float sred[4];
    if ((threadIdx.x & 63) == 0) sred[threadIdx.x >> 6] = v;
    __syncthreads();
    if (threadIdx.x == 0) atomicAdd(out, sred[0] + sred[1] + sred[2] + sred[3]);
}

extern "C" void kernel_launch(void* const* d_in, const int* in_sizes, int n_in,
                              void* d_out, int out_size, void* d_ws, size_t ws_size,
                              hipStream_t stream) {
    const float* feat = (const float*)d_in[0];
    const int* labels = (const int*)d_in[1];
    float* out        = (float*)d_out;
    char* ws          = (char*)d_ws;

    ushort* fb      = (ushort*)ws;                                   // 2 MB
    float* g_se     = (float*)(ws + (size_t)2 * 1024 * 1024);        // [32][NN] = 1 MB
    float* selfdot  = g_se + NSPLIT * NN;                            // NN f32
    float* S        = selfdot + NN;                                  // 12800 f32 (k_csum plain-stores)
    int*   counts   = (int*)(S + NCLS * DD);                         // 100 i32  (k_csum plain-stores)

    k_norm<<<NN / 4, 256, 0, stream>>>(feat, fb, selfdot, out);
    k_csum<<<NCLS, 256, 0, stream>>>(fb, labels, S, counts);
    k_main<<<NRB * NSPLIT, 256, 0, stream>>>(fb, g_se);
    k_final<<<NN / 256, 256, 0, stream>>>(fb, labels, g_se, S, counts, selfdot, out);
}

// Round 12
// 82.966 us; speedup vs baseline: 2.9194x; 1.2387x over previous
//
#include <hip/hip_runtime.h>
#include <hip/hip_bf16.h>
#include <hip/hip_fp8.h>
#include <math.h>

#define NB 4096     // batch (= B); label of row n is labels[n % NB]
#define NN 8192     // N = B * n_views
#define DD 128      // feature dim (bytes per fp8 row)
#define NCLS 100    // label values 0..99
#define NSPLIT 16   // j-splits; 512 cols per block
#define CHUNK 64    // cols per LDS-staged chunk
#define NCHUNK 8    // 512 / 64

constexpr float INV_T = 14.285714285714286f;   // 1/0.07 (= subtracted row max M)
constexpr float EC1   = 20.609929155556620f;   // INV_T * log2(e)
constexpr float EC0   = -20.609929155556620f;  // -INV_T * log2(e)
constexpr float LN2   = 0.6931471805599453f;

typedef unsigned char u8;
typedef __attribute__((ext_vector_type(8))) int   v8i;
typedef __attribute__((ext_vector_type(4))) int   v4i;
typedef __attribute__((ext_vector_type(4))) float f32x4;

// ---- kernel 1: L2-normalize rows -> fp8 e4m3 + selfdot of quantized row ----
__global__ __launch_bounds__(256) void k_norm(const float* __restrict__ feat,
                                              u8* __restrict__ fb8,
                                              float* __restrict__ selfdot,
                                              float* __restrict__ out) {
    const int gid = blockIdx.x * 256 + threadIdx.x;
    if (gid == 0) out[0] = 0.0f;               // k_final atomicAdds into out
    const int r    = gid >> 6;                 // one wave per row
    const int lane = threadIdx.x & 63;
    const float2 v = ((const float2*)(feat + (size_t)r * DD))[lane];
    float ss = v.x * v.x + v.y * v.y;
#pragma unroll
    for (int off = 1; off < 64; off <<= 1) ss += __shfl_xor(ss, off, 64);
    const float scale = 1.0f / fmaxf(sqrtf(ss), 1e-12f);
    const __hip_fp8_e4m3 qx(v.x * scale), qy(v.y * scale);  // OCP e4m3fn
    const unsigned short pack = (unsigned short)qx.__x |
                                ((unsigned short)qy.__x << 8);
    ((unsigned short*)(fb8 + (size_t)r * DD))[lane] = pack;
    // self-dot of the QUANTIZED row (matches the MFMA diagonal)
    const float xb = (float)qx, yb = (float)qy;
    float s2 = xb * xb + yb * yb;
#pragma unroll
    for (int off = 1; off < 64; off <<= 1) s2 += __shfl_xor(s2, off, 64);
    if (lane == 0) selfdot[r] = s2;
}

// stage one 64-col chunk's fp8 B-fragments into LDS, fragment-major.
// Pair p = jt*2 + half (8 pairs of 1 KB); wave w stages pairs 2w, 2w+1.
// LDS dst = wave-uniform base + lane*16 (HW rule); per-lane GLOBAL address
// does the fragment gather: lane l wants row (jb+jt*16+(l&15)), bytes
// (l>>4)*32 + half*16.
__device__ __forceinline__ void stage_chunk(const u8* __restrict__ fb8, u8* sbuf,
                                            int jb, int w, int n15, int q) {
#pragma unroll
    for (int h = 0; h < 2; ++h) {
        const int p = w * 2 + h;
        const u8* g = fb8 + (size_t)(jb + (p >> 1) * 16 + n15) * DD + q * 32 + (p & 1) * 16;
        __builtin_amdgcn_global_load_lds(
            (const __attribute__((address_space(1))) void*)g,
            (__attribute__((address_space(3))) void*)(sbuf + p * 1024),
            16, 0, 0);
    }
}

// ---- kernel 2: F*F^T via MX-fp8 K=128 MFMA, fused exp + masked-possum ----
// Block: 128 rows x 512 cols; 4 waves of 32 rows. Grid 1024 = 64 rb x 16 js.
// Per j-tile: 2 ds_read_b128 + 2 single-K MFMAs (no K-chain) + 8-elem epilogue.
// Plain per-split stores; no atomics/fences (R8 lesson); no ct accumulator
// (k_final rebuilds counts via histogram).
__global__ __launch_bounds__(256, 4) void k_main(const u8* __restrict__ fb8,
                                                 const int* __restrict__ labels,
                                                 float* __restrict__ g_se,
                                                 float* __restrict__ g_ps) {
    __shared__ u8 sB[2][CHUNK * DD];   // 2 x 8 KB, fragment-major
    __shared__ int slab[512];          // labels of this block's col range

    const int tid  = threadIdx.x;
    const int lane = tid & 63;
    const int w    = tid >> 6;                  // 0..3
    const int rb   = blockIdx.x >> 4;           // 0..63
    const int js   = blockIdx.x & (NSPLIT - 1); // 0..15
    const int i0   = rb * 128 + w * 32;
    const int jb0  = js * 512;
    const int q    = lane >> 4;
    const int n15  = lane & 15;

    slab[tid]       = labels[(jb0 + tid) & (NB - 1)];
    slab[tid + 256] = labels[(jb0 + tid + 256) & (NB - 1)];

    // A fragments: 2 row-tiles, full K=128 per tile (8 VGPRs each).
    // Operand layout: lane l holds A[row=l&15][k=(l>>4)*32 + 0..31].
    v8i af[2];
#pragma unroll
    for (int tt = 0; tt < 2; ++tt) {
        const u8* rp = fb8 + (size_t)(i0 + tt * 16 + n15) * DD + q * 32;
        const v4i lo = *(const v4i*)rp;
        const v4i hi = *(const v4i*)(rp + 16);
        v8i a;
#pragma unroll
        for (int k = 0; k < 4; ++k) { a[k] = lo[k]; a[4 + k] = hi[k]; }
        af[tt] = a;
    }
    // labels of this lane's 8 accumulator rows (C/D map: row = q*4+r)
    int labi[8];
#pragma unroll
    for (int tt = 0; tt < 2; ++tt)
#pragma unroll
        for (int r = 0; r < 4; ++r)
            labi[tt * 4 + r] = labels[(i0 + tt * 16 + q * 4 + r) & (NB - 1)];

    float a_se[8] = {}, a_ps[8] = {};

    stage_chunk(fb8, &sB[0][0], jb0, w, n15, q);
    __syncthreads();

    for (int c = 0; c < NCHUNK; ++c) {
        if (c + 1 < NCHUNK)
            stage_chunk(fb8, &sB[(c + 1) & 1][0], jb0 + (c + 1) * CHUNK, w, n15, q);
        const u8* sb = &sB[c & 1][0];
        const int crel = c * CHUNK;
#pragma unroll
        for (int jt = 0; jt < 4; ++jt) {
            const v4i lo = *(const v4i*)(sb + (jt * 2 + 0) * 1024 + lane * 16);
            const v4i hi = *(const v4i*)(sb + (jt * 2 + 1) * 1024 + lane * 16);
            v8i bb;
#pragma unroll
            for (int k = 0; k < 4; ++k) { bb[k] = lo[k]; bb[4 + k] = hi[k]; }
            const int labj = slab[crel + jt * 16 + n15];
            f32x4 a0 = {0.f, 0.f, 0.f, 0.f}, a1 = {0.f, 0.f, 0.f, 0.f};
            // cbsz=0 (A=fp8 e4m3), blgp=0 (B=fp8); scale bytes 0x7F = e8m0 1.0
            a0 = __builtin_amdgcn_mfma_scale_f32_16x16x128_f8f6f4(
                     af[0], bb, a0, 0, 0, 0, 0x7F7F7F7F, 0, 0x7F7F7F7F);
            a1 = __builtin_amdgcn_mfma_scale_f32_16x16x128_f8f6f4(
                     af[1], bb, a1, 0, 0, 0, 0x7F7F7F7F, 0, 0x7F7F7F7F);
#pragma unroll
            for (int r = 0; r < 4; ++r) {
                const float d0 = a0[r], d1 = a1[r];
                a_se[r]     += __builtin_amdgcn_exp2f(fmaf(d0, EC1, EC0));
                a_se[4 + r] += __builtin_amdgcn_exp2f(fmaf(d1, EC1, EC0));
                a_ps[r]     += (labi[r]     == labj) ? d0 : 0.0f;  // raw dot; shifted in k_final
                a_ps[4 + r] += (labi[4 + r] == labj) ? d1 : 0.0f;
            }
        }
        __syncthreads();
    }

    // 16 lanes per quad share the same rows; reduce, single plain store each
#pragma unroll
    for (int s = 0; s < 8; ++s) {
        float v1 = a_se[s], v2 = a_ps[s];
#pragma unroll
        for (int off = 1; off < 16; off <<= 1) {
            v1 += __shfl_xor(v1, off, 64);
            v2 += __shfl_xor(v2, off, 64);
        }
        if (n15 == 0) {
            const int row = i0 + (s >> 2) * 16 + q * 4 + (s & 3);
            g_se[js * NN + row] = v1;
            g_ps[js * NN + row] = v2;
        }
    }
}

// ---- kernel 3: per-row loss; counts via LDS histogram; atomic mean ----
__global__ __launch_bounds__(256) void k_final(const int* __restrict__ labels,
                                               const float* __restrict__ g_se,
                                               const float* __restrict__ g_ps,
                                               const float* __restrict__ selfdot,
                                               float* __restrict__ out) {
    __shared__ int hist[NCLS];
    const int tid = threadIdx.x;
    for (int i = tid; i < NCLS; i += 256) hist[i] = 0;
    __syncthreads();
    for (int b = tid; b < NB; b += 256) atomicAdd(&hist[labels[b]], 1);
    __syncthreads();

    const int r = blockIdx.x * 256 + tid;
    const int c = labels[r & (NB - 1)];
    float se = 0.f, ps = 0.f;
#pragma unroll
    for (int t = 0; t < NSPLIT; ++t) {
        se += g_se[t * NN + r];
        ps += g_ps[t * NN + r];
    }
    const float sd = selfdot[r];
    se -= __builtin_amdgcn_exp2f(fmaf(sd, EC1, EC0));  // drop diagonal from sumexp
    const float ct = (float)(2 * hist[c] - 1);         // positives excl. diagonal
    const float possum = INV_T * ((ps - sd) - ct);     // sum_pos (l_ij - M)
    const float lg  = __builtin_amdgcn_logf(se + 1e-12f) * LN2;
    const float mlpp = (possum - ct * lg) / fmaxf(ct, 1.0f);
    float v = -mlpp * (1.0f / (float)NN);
#pragma unroll
    for (int off = 1; off < 64; off <<= 1) v += __shfl_xor(v, off, 64);
    __shared__ float sred[4];
    if ((tid & 63) == 0) sred[tid >> 6] = v;
    __syncthreads();
    if (tid == 0) atomicAdd(out, sred[0] + sred[1] + sred[2] + sred[3]);
}

extern "C" void kernel_launch(void* const* d_in, const int* in_sizes, int n_in,
                              void* d_out, int out_size, void* d_ws, size_t ws_size,
                              hipStream_t stream) {
    const float* feat = (const float*)d_in[0];
    const int* labels = (const int*)d_in[1];
    float* out        = (float*)d_out;
    char* ws          = (char*)d_ws;

    u8* fb8         = (u8*)ws;                                       // 1 MB fp8
    float* g_se     = (float*)(ws + (size_t)1 * 1024 * 1024);        // [16][NN] 512 KB
    float* g_ps     = g_se + NSPLIT * NN;                            // 512 KB
    float* selfdot  = g_ps + NSPLIT * NN;                            // NN f32

    k_norm<<<NN / 4, 256, 0, stream>>>(feat, fb8, selfdot, out);
    k_main<<<(NN / 128) * NSPLIT, 256, 0, stream>>>(fb8, labels, g_se, g_ps);
    k_final<<<NN / 256, 256, 0, stream>>>(labels, g_se, g_ps, selfdot, out);
}